// Round 1
// baseline (412.083 us; speedup 1.0000x reference)
//
#include <hip/hip_runtime.h>
#include <hip/hip_bf16.h>

// ---------------------------------------------------------------------------
// MoE: router (argmax over 8 experts) + capacity drop + per-expert linear.
// Round 0: correctness-first fp32 pipeline. GEMM is a classic 64x64x16 LDS
// tile with 4x4 per-thread micro-tile; swap-in point for MFMA later.
// ---------------------------------------------------------------------------

// ---------------- Router: one wave per token ----------------
__global__ void router_kernel(const float* __restrict__ x,
                              const float* __restrict__ Wr,
                              const float* __restrict__ br,
                              int* __restrict__ ids,
                              int N, int D) {
    int gtid = blockIdx.x * blockDim.x + threadIdx.x;
    int token = gtid >> 6;
    int lane  = threadIdx.x & 63;
    if (token >= N) return;

    const float* xr = x + (size_t)token * D;
    float acc[8];
#pragma unroll
    for (int e = 0; e < 8; ++e) acc[e] = 0.f;

    for (int d0 = 0; d0 < D; d0 += 64) {
        float xv = xr[d0 + lane];
#pragma unroll
        for (int e = 0; e < 8; ++e)
            acc[e] += xv * Wr[e * D + d0 + lane];
    }
    // wave-wide tree reduce each accumulator
#pragma unroll
    for (int e = 0; e < 8; ++e) {
        float v = acc[e];
        for (int off = 32; off > 0; off >>= 1)
            v += __shfl_xor(v, off, 64);
        acc[e] = v;
    }
    if (lane == 0) {
        int best = 0;
        float bv = acc[0] + br[0];
#pragma unroll
        for (int e = 1; e < 8; ++e) {
            float lv = acc[e] + br[e];
            if (lv > bv) { bv = lv; best = e; }  // strict > keeps first max (argmax tie rule)
        }
        ids[token] = best;
    }
}

// ---------------- Per-block expert histogram ----------------
__global__ void hist_kernel(const int* __restrict__ ids,
                            int* __restrict__ blockHist, int N) {
    __shared__ int h[8];
    if (threadIdx.x < 8) h[threadIdx.x] = 0;
    __syncthreads();
    int n = blockIdx.x * 256 + threadIdx.x;
    if (n < N) atomicAdd(&h[ids[n]], 1);
    __syncthreads();
    if (threadIdx.x < 8)
        blockHist[blockIdx.x * 8 + threadIdx.x] = h[threadIdx.x];
}

// ---------------- Single-block exclusive scan over blocks ----------------
__global__ void scan_kernel(const int* __restrict__ blockHist,
                            int* __restrict__ blockOff,
                            int* __restrict__ kcnt,
                            const int* __restrict__ capacity,
                            int nb) {
    int e = threadIdx.x;
    if (e < 8) {
        int run = 0;
        for (int b = 0; b < nb; ++b) {
            blockOff[b * 8 + e] = run;
            run += blockHist[b * 8 + e];
        }
        int cap = capacity[0];
        kcnt[e] = run < cap ? run : cap;
    }
}

// ---------------- Rank + compact gather lists ----------------
__global__ void rank_kernel(const int* __restrict__ ids,
                            const int* __restrict__ blockOff,
                            const int* __restrict__ capacity,
                            int* __restrict__ gather,
                            int N) {
    __shared__ int waveHist[4][8];
    int tid  = threadIdx.x;           // 256 threads = 4 waves
    int n    = blockIdx.x * 256 + tid;
    int lane = tid & 63;
    int wave = tid >> 6;

    int id = (n < N) ? ids[n] : -1;
    int within = 0;
    unsigned long long lt = (1ull << lane) - 1ull;
#pragma unroll
    for (int e = 0; e < 8; ++e) {
        unsigned long long m = __ballot(id == e);
        if (lane == e) waveHist[wave][e] = __popcll(m);
        if (id == e)   within = __popcll(m & lt);
    }
    __syncthreads();
    if (n < N) {
        int prior = blockOff[blockIdx.x * 8 + id];
        for (int w = 0; w < wave; ++w) prior += waveHist[w][id];
        int rank = prior + within + 1;            // 1-based inclusive
        if (rank <= capacity[0])
            gather[id * N + (rank - 1)] = n;      // slots 0..kcnt-1 fully written
    }
}

// ---------------- Expert GEMM: Y[tok, f] = x[tok,:] . We[e,f,:] + be[e,f] ---
#define BM 64
#define BN 64
#define BK 16
__global__ __launch_bounds__(256) void expert_gemm(
        const float* __restrict__ x,
        const float* __restrict__ We,
        const float* __restrict__ be,
        const int* __restrict__ gather,
        const int* __restrict__ kcnt,
        float* __restrict__ out,
        int N, int D, int F) {
    int e = blockIdx.z;
    int cnt = kcnt[e];
    int row0 = blockIdx.y * BM;
    if (row0 >= cnt) return;
    int col0 = blockIdx.x * BN;

    const float* W = We + (size_t)e * F * D;

    __shared__ float As[BK][BM];
    __shared__ float Bs[BK][BN];

    int tid = threadIdx.x;           // 256
    int tx = tid & 15;               // 0..15 -> cols tx*4..tx*4+3
    int ty = tid >> 4;               // 0..15 -> rows ty*4..ty*4+3

    int rA  = tid >> 4;              // load row within tile (0..15, +16*i)
    int kkA = tid & 15;              // load k within tile

    // token indices for the 4 A rows this thread loads
    int trow[4];
#pragma unroll
    for (int i = 0; i < 4; ++i) {
        int gr = row0 + rA + i * 16;
        trow[i] = (gr < cnt) ? gather[e * N + gr] : -1;
    }

    float acc[4][4];
#pragma unroll
    for (int i = 0; i < 4; ++i)
#pragma unroll
        for (int j = 0; j < 4; ++j) acc[i][j] = 0.f;

    for (int k0 = 0; k0 < D; k0 += BK) {
#pragma unroll
        for (int i = 0; i < 4; ++i) {
            float v = 0.f;
            if (trow[i] >= 0) v = x[(size_t)trow[i] * D + k0 + kkA];
            As[kkA][rA + i * 16] = v;
        }
#pragma unroll
        for (int i = 0; i < 4; ++i) {
            int f = rA + i * 16;
            Bs[kkA][f] = W[(size_t)(col0 + f) * D + k0 + kkA];
        }
        __syncthreads();
#pragma unroll
        for (int kk = 0; kk < BK; ++kk) {
            float a[4], b[4];
#pragma unroll
            for (int i = 0; i < 4; ++i) a[i] = As[kk][ty * 4 + i];
#pragma unroll
            for (int j = 0; j < 4; ++j) b[j] = Bs[kk][tx * 4 + j];
#pragma unroll
            for (int i = 0; i < 4; ++i)
#pragma unroll
                for (int j = 0; j < 4; ++j)
                    acc[i][j] += a[i] * b[j];
        }
        __syncthreads();
    }

    // epilogue: bias + scatter to out rows (float4 stores)
#pragma unroll
    for (int i = 0; i < 4; ++i) {
        int gr = row0 + ty * 4 + i;
        if (gr >= cnt) continue;
        int tokn = gather[e * N + gr];
        float4 v;
        v.x = acc[i][0] + be[e * F + col0 + tx * 4 + 0];
        v.y = acc[i][1] + be[e * F + col0 + tx * 4 + 1];
        v.z = acc[i][2] + be[e * F + col0 + tx * 4 + 2];
        v.w = acc[i][3] + be[e * F + col0 + tx * 4 + 3];
        float* orow = out + (size_t)tokn * F + col0 + tx * 4;
        *reinterpret_cast<float4*>(orow) = v;
    }
}

extern "C" void kernel_launch(void* const* d_in, const int* in_sizes, int n_in,
                              void* d_out, int out_size, void* d_ws, size_t ws_size,
                              hipStream_t stream) {
    const float* x        = (const float*)d_in[0];
    const float* Wr       = (const float*)d_in[1];
    const float* br       = (const float*)d_in[2];
    const float* We       = (const float*)d_in[3];
    const float* be       = (const float*)d_in[4];
    const int*   capacity = (const int*)d_in[5];

    int E = in_sizes[2];               // 8
    int D = in_sizes[1] / E;           // 1024
    int N = in_sizes[0] / D;           // 8192
    int F = in_sizes[4] / E;           // 1024

    float* out = (float*)d_out;

    // workspace layout
    int* ids       = (int*)d_ws;
    int  nb        = (N + 255) / 256;
    int* blockHist = ids + N;
    int* blockOff  = blockHist + nb * 8;
    int* kcnt      = blockOff + nb * 8;
    int* gather    = kcnt + 8;

    // 1. passthrough default: out = x
    hipMemcpyAsync(out, x, (size_t)N * D * sizeof(float),
                   hipMemcpyDeviceToDevice, stream);

    // 2. router
    {
        int waves_per_block = 4;                     // 256 threads
        int blocks = (N + waves_per_block - 1) / waves_per_block;
        router_kernel<<<blocks, 256, 0, stream>>>(x, Wr, br, ids, N, D);
    }

    // 3. capacity bookkeeping
    hist_kernel<<<nb, 256, 0, stream>>>(ids, blockHist, N);
    scan_kernel<<<1, 64, 0, stream>>>(blockHist, blockOff, kcnt, capacity, nb);
    rank_kernel<<<nb, 256, 0, stream>>>(ids, blockOff, capacity, gather, N);

    // 4. expert GEMM (blocks beyond kcnt early-exit; 128 row tiles covers
    //    any capacity up to N=8192)
    {
        dim3 grid(F / BN, 128, E);
        expert_gemm<<<grid, 256, 0, stream>>>(x, We, be, gather, kcnt, out, N, D, F);
    }
}

// Round 2
// 94.098 us; speedup vs baseline: 4.3793x; 4.3793x over previous
//
#include <hip/hip_runtime.h>
#include <hip/hip_bf16.h>

// ---------------------------------------------------------------------------
// MoE: router (argmax over 8 experts) + capacity drop + per-expert linear.
// Round 2: bf16 MFMA expert GEMM (m97 structure: 128x128 tile, BK=32,
// global_load_lds width-16, mfma_f32_16x16x32_bf16), compact gather of kept
// tokens, dropped-row-only passthrough. fp32 fallback path if ws too small.
// ---------------------------------------------------------------------------

typedef short short8_t __attribute__((ext_vector_type(8)));
typedef float f32x4_t  __attribute__((ext_vector_type(4)));

typedef const unsigned int __attribute__((address_space(1))) gu32;
typedef unsigned int       __attribute__((address_space(3))) lu32;

__device__ __forceinline__ void async_load16(const void* gptr, void* lptr) {
    __builtin_amdgcn_global_load_lds((gu32*)gptr, (lu32*)lptr, 16, 0, 0);
}

// ---------------- Router: one wave per token (fp32, exact argmax) ----------
__global__ void router_kernel(const float* __restrict__ x,
                              const float* __restrict__ Wr,
                              const float* __restrict__ br,
                              int* __restrict__ ids,
                              int N, int D) {
    int gtid = blockIdx.x * blockDim.x + threadIdx.x;
    int token = gtid >> 6;
    int lane  = threadIdx.x & 63;
    if (token >= N) return;

    const float* xr = x + (size_t)token * D;
    float acc[8];
#pragma unroll
    for (int e = 0; e < 8; ++e) acc[e] = 0.f;

    for (int d0 = 0; d0 < D; d0 += 64) {
        float xv = xr[d0 + lane];
#pragma unroll
        for (int e = 0; e < 8; ++e)
            acc[e] += xv * Wr[e * D + d0 + lane];
    }
#pragma unroll
    for (int e = 0; e < 8; ++e) {
        float v = acc[e];
        for (int off = 32; off > 0; off >>= 1)
            v += __shfl_xor(v, off, 64);
        acc[e] = v;
    }
    if (lane == 0) {
        int best = 0;
        float bv = acc[0] + br[0];
#pragma unroll
        for (int e = 1; e < 8; ++e) {
            float lv = acc[e] + br[e];
            if (lv > bv) { bv = lv; best = e; }  // strict >: first max (argmax rule)
        }
        ids[token] = best;
    }
}

// ---------------- Per-block expert histogram ----------------
__global__ void hist_kernel(const int* __restrict__ ids,
                            int* __restrict__ blockHist, int N) {
    __shared__ int h[8];
    if (threadIdx.x < 8) h[threadIdx.x] = 0;
    __syncthreads();
    int n = blockIdx.x * 256 + threadIdx.x;
    if (n < N) atomicAdd(&h[ids[n]], 1);
    __syncthreads();
    if (threadIdx.x < 8)
        blockHist[blockIdx.x * 8 + threadIdx.x] = h[threadIdx.x];
}

// ---------------- Single-block scan: block offsets, kcnt, expert bases -----
__global__ void scan_kernel(const int* __restrict__ blockHist,
                            int* __restrict__ blockOff,
                            int* __restrict__ kcnt,
                            int* __restrict__ ebase,
                            const int* __restrict__ capacity,
                            int nb) {
    __shared__ int sk[8];
    int e = threadIdx.x;
    if (e < 8) {
        int run = 0;
        for (int b = 0; b < nb; ++b) {
            blockOff[b * 8 + e] = run;
            run += blockHist[b * 8 + e];
        }
        int cap = capacity[0];
        int k = run < cap ? run : cap;
        kcnt[e] = k;
        sk[e] = k;
    }
    __syncthreads();
    if (e == 0) {
        int run = 0;
        for (int i = 0; i < 8; ++i) { ebase[i] = run; run += sk[i]; }
    }
}

// ---------------- Rank + compact gather lists + dropped list ---------------
__global__ void rank_kernel(const int* __restrict__ ids,
                            const int* __restrict__ blockOff,
                            const int* __restrict__ capacity,
                            int* __restrict__ gather,
                            int* __restrict__ dropped,   // may be null
                            int* __restrict__ ndropped,  // may be null
                            int N) {
    __shared__ int waveHist[4][8];
    int tid  = threadIdx.x;           // 256 threads = 4 waves
    int n    = blockIdx.x * 256 + tid;
    int lane = tid & 63;
    int wave = tid >> 6;

    int id = (n < N) ? ids[n] : -1;
    int within = 0;
    unsigned long long lt = (1ull << lane) - 1ull;
#pragma unroll
    for (int e = 0; e < 8; ++e) {
        unsigned long long m = __ballot(id == e);
        if (lane == e) waveHist[wave][e] = __popcll(m);
        if (id == e)   within = __popcll(m & lt);
    }
    __syncthreads();
    if (n < N) {
        int prior = blockOff[blockIdx.x * 8 + id];
        for (int w = 0; w < wave; ++w) prior += waveHist[w][id];
        int rank = prior + within + 1;            // 1-based inclusive
        if (rank <= capacity[0]) {
            gather[id * N + (rank - 1)] = n;      // slots 0..kcnt-1 fully written
        } else if (ndropped != nullptr) {
            int di = atomicAdd(ndropped, 1);      // order-free: it's just a set
            dropped[di] = n;
        }
    }
}

// ---------------- We fp32 -> bf16 ----------------
__global__ void conv_we_kernel(const float* __restrict__ We,
                               __hip_bfloat16* __restrict__ We16,
                               size_t n) {
    size_t i = ((size_t)blockIdx.x * blockDim.x + threadIdx.x) * 8;
    size_t stride = (size_t)gridDim.x * blockDim.x * 8;
    for (; i < n; i += stride) {
        float4 v0 = *reinterpret_cast<const float4*>(We + i);
        float4 v1 = *reinterpret_cast<const float4*>(We + i + 4);
        union { __hip_bfloat16 h[8]; uint4 u; } t;
        t.h[0] = __float2bfloat16(v0.x); t.h[1] = __float2bfloat16(v0.y);
        t.h[2] = __float2bfloat16(v0.z); t.h[3] = __float2bfloat16(v0.w);
        t.h[4] = __float2bfloat16(v1.x); t.h[5] = __float2bfloat16(v1.y);
        t.h[6] = __float2bfloat16(v1.z); t.h[7] = __float2bfloat16(v1.w);
        *reinterpret_cast<uint4*>(We16 + i) = t.u;
    }
}

// ---------------- Gather kept rows of x -> compact bf16 Xg + tokmap --------
__global__ void gather_conv_x_kernel(const float* __restrict__ x,
                                     const int* __restrict__ gather,
                                     const int* __restrict__ kcnt,
                                     const int* __restrict__ ebase,
                                     int* __restrict__ tokmap,
                                     __hip_bfloat16* __restrict__ Xg,
                                     int N, int D) {
    int e = blockIdx.y;
    int cnt = kcnt[e], base = ebase[e];
    int r0 = blockIdx.x * 16;
    if (r0 >= cnt) return;
    int t = threadIdx.x;               // 256 threads: cols t*4..t*4+3
    for (int i = 0; i < 16; ++i) {
        int gr = r0 + i;
        if (gr >= cnt) break;
        int tok = gather[e * N + gr];
        if (t == 0) tokmap[base + gr] = tok;
        float4 v = *reinterpret_cast<const float4*>(x + (size_t)tok * D + t * 4);
        union { __hip_bfloat16 h[4]; uint2 u; } tt;
        tt.h[0] = __float2bfloat16(v.x); tt.h[1] = __float2bfloat16(v.y);
        tt.h[2] = __float2bfloat16(v.z); tt.h[3] = __float2bfloat16(v.w);
        *reinterpret_cast<uint2*>(Xg + (size_t)(base + gr) * D + t * 4) = tt.u;
    }
}

// ---------------- Passthrough for dropped rows only ----------------
__global__ void copy_dropped_kernel(const float* __restrict__ x,
                                    const int* __restrict__ dropped,
                                    const int* __restrict__ ndropped,
                                    float* __restrict__ out, int D) {
    int nd = *ndropped;
    for (int i = blockIdx.x; i < nd; i += gridDim.x) {
        int tok = dropped[i];
        const float4* src = reinterpret_cast<const float4*>(x + (size_t)tok * D);
        float4* dst = reinterpret_cast<float4*>(out + (size_t)tok * D);
        dst[threadIdx.x] = src[threadIdx.x];   // 256 threads x float4 = 1024 f
    }
}

// ---------------- MFMA expert GEMM (m97 structure) ----------------
// C[tok, f] = Xg[row,:] . We16[e,f,:] + be[e,f], scattered to out via tokmap.
#define TM 128
#define TN 128
#define TK 32
__global__ __launch_bounds__(256) void expert_gemm_mfma(
        const __hip_bfloat16* __restrict__ Xg,
        const __hip_bfloat16* __restrict__ We16,
        const float* __restrict__ be,
        const int* __restrict__ kcnt,
        const int* __restrict__ ebase,
        const int* __restrict__ tokmap,
        float* __restrict__ out,
        int D, int F) {
    int e = blockIdx.z;
    int cnt = kcnt[e];
    int row0 = blockIdx.y * TM;
    if (row0 >= cnt) return;
    int col0 = blockIdx.x * TN;
    int base = ebase[e];

    __shared__ __hip_bfloat16 As[TM][TK];   // 8 KB
    __shared__ __hip_bfloat16 Bs[TN][TK];   // 8 KB

    int tid  = threadIdx.x;
    int lane = tid & 63;
    int wave = tid >> 6;                    // 4 waves, 2x2 over 64x64 subtiles
    int wr = wave >> 1, wc = wave & 1;

    const __hip_bfloat16* Asrc = Xg + (size_t)(base + row0) * D;
    const __hip_bfloat16* Bsrc = We16 + ((size_t)e * F + col0) * D;

    f32x4_t zero = {0.f, 0.f, 0.f, 0.f};
    f32x4_t acc[4][4];
#pragma unroll
    for (int m = 0; m < 4; ++m)
#pragma unroll
        for (int n = 0; n < 4; ++n) acc[m][n] = zero;

    int kgrp = (lane >> 4) * 8;             // k offset of this lane's fragment
    int rA = wr * 64 + (lane & 15);
    int rB = wc * 64 + (lane & 15);
    const short* Ab = reinterpret_cast<const short*>(&As[0][0]);
    const short* Bb = reinterpret_cast<const short*>(&Bs[0][0]);

    for (int k0 = 0; k0 < D; k0 += TK) {
        // stage A,B tiles: 512 16B-chunks each half; chunk c -> row c>>2, kq c&3
#pragma unroll
        for (int i = 0; i < 2; ++i) {
            int c  = i * 256 + tid;
            int r  = c >> 2, kq = c & 3;
            // LDS dest must be wave-uniform base; lane writes base + lane*16
            char* ldsA = (char*)&As[0][0] + (size_t)(i * 256 + wave * 64) * 16;
            char* ldsB = (char*)&Bs[0][0] + (size_t)(i * 256 + wave * 64) * 16;
            async_load16(Asrc + (size_t)r * D + k0 + kq * 8, ldsA);
            async_load16(Bsrc + (size_t)r * D + k0 + kq * 8, ldsB);
        }
        __syncthreads();                    // drains vmcnt before LDS reads

        short8_t a[4], b[4];
#pragma unroll
        for (int m = 0; m < 4; ++m)
            a[m] = *reinterpret_cast<const short8_t*>(&Ab[(rA + m * 16) * TK + kgrp]);
#pragma unroll
        for (int n = 0; n < 4; ++n)
            b[n] = *reinterpret_cast<const short8_t*>(&Bb[(rB + n * 16) * TK + kgrp]);
#pragma unroll
        for (int m = 0; m < 4; ++m)
#pragma unroll
            for (int n = 0; n < 4; ++n)
                acc[m][n] = __builtin_amdgcn_mfma_f32_16x16x32_bf16(
                    a[m], b[n], acc[m][n], 0, 0, 0);
        __syncthreads();
    }

    // epilogue: D-frag row = token-dim (lane>>4)*4+r, col = f-dim lane&15
    int fcol = col0 + wc * 64 + (lane & 15);
#pragma unroll
    for (int m = 0; m < 4; ++m) {
        int gr0 = row0 + wr * 64 + m * 16 + (lane >> 4) * 4;
#pragma unroll
        for (int r = 0; r < 4; ++r) {
            int gr = gr0 + r;
            if (gr >= cnt) continue;
            int tok = tokmap[base + gr];
#pragma unroll
            for (int n = 0; n < 4; ++n) {
                int f = fcol + n * 16;
                out[(size_t)tok * F + f] = acc[m][n][r] + be[e * F + f];
            }
        }
    }
}

// ---------------- fp32 fallback GEMM (round-1, known-good) ----------------
#define BM 64
#define BN 64
#define BK 16
__global__ __launch_bounds__(256) void expert_gemm_f32(
        const float* __restrict__ x,
        const float* __restrict__ We,
        const float* __restrict__ be,
        const int* __restrict__ gather,
        const int* __restrict__ kcnt,
        float* __restrict__ out,
        int N, int D, int F) {
    int e = blockIdx.z;
    int cnt = kcnt[e];
    int row0 = blockIdx.y * BM;
    if (row0 >= cnt) return;
    int col0 = blockIdx.x * BN;

    const float* W = We + (size_t)e * F * D;
    __shared__ float As[BK][BM];
    __shared__ float Bs[BK][BN];

    int tid = threadIdx.x;
    int tx = tid & 15, ty = tid >> 4;
    int rA = tid >> 4, kkA = tid & 15;

    int trow[4];
#pragma unroll
    for (int i = 0; i < 4; ++i) {
        int gr = row0 + rA + i * 16;
        trow[i] = (gr < cnt) ? gather[e * N + gr] : -1;
    }
    float acc[4][4];
#pragma unroll
    for (int i = 0; i < 4; ++i)
#pragma unroll
        for (int j = 0; j < 4; ++j) acc[i][j] = 0.f;

    for (int k0 = 0; k0 < D; k0 += BK) {
#pragma unroll
        for (int i = 0; i < 4; ++i) {
            float v = 0.f;
            if (trow[i] >= 0) v = x[(size_t)trow[i] * D + k0 + kkA];
            As[kkA][rA + i * 16] = v;
        }
#pragma unroll
        for (int i = 0; i < 4; ++i) {
            int f = rA + i * 16;
            Bs[kkA][f] = W[(size_t)(col0 + f) * D + k0 + kkA];
        }
        __syncthreads();
#pragma unroll
        for (int kk = 0; kk < BK; ++kk) {
            float a[4], b[4];
#pragma unroll
            for (int i = 0; i < 4; ++i) a[i] = As[kk][ty * 4 + i];
#pragma unroll
            for (int j = 0; j < 4; ++j) b[j] = Bs[kk][tx * 4 + j];
#pragma unroll
            for (int i = 0; i < 4; ++i)
#pragma unroll
                for (int j = 0; j < 4; ++j)
                    acc[i][j] += a[i] * b[j];
        }
        __syncthreads();
    }
#pragma unroll
    for (int i = 0; i < 4; ++i) {
        int gr = row0 + ty * 4 + i;
        if (gr >= cnt) continue;
        int tokn = gather[e * N + gr];
        float4 v;
        v.x = acc[i][0] + be[e * F + col0 + tx * 4 + 0];
        v.y = acc[i][1] + be[e * F + col0 + tx * 4 + 1];
        v.z = acc[i][2] + be[e * F + col0 + tx * 4 + 2];
        v.w = acc[i][3] + be[e * F + col0 + tx * 4 + 3];
        *reinterpret_cast<float4*>(out + (size_t)tokn * F + col0 + tx * 4) = v;
    }
}

extern "C" void kernel_launch(void* const* d_in, const int* in_sizes, int n_in,
                              void* d_out, int out_size, void* d_ws, size_t ws_size,
                              hipStream_t stream) {
    const float* x        = (const float*)d_in[0];
    const float* Wr       = (const float*)d_in[1];
    const float* br       = (const float*)d_in[2];
    const float* We       = (const float*)d_in[3];
    const float* be       = (const float*)d_in[4];
    const int*   capacity = (const int*)d_in[5];

    int E = in_sizes[2];               // 8
    int D = in_sizes[1] / E;           // 1024
    int N = in_sizes[0] / D;           // 8192
    int F = in_sizes[4] / E;           // 1024
    int nb = (N + 255) / 256;

    float* out = (float*)d_out;

    // ---- workspace layout (meta first so the fallback fits in small ws) ----
    char* w = (char*)d_ws;
    size_t off = 0;
    auto take = [&](size_t bytes) {
        size_t p = off;
        off = (off + bytes + 255) & ~(size_t)255;
        return p;
    };
    int* ids       = (int*)(w + take((size_t)N * 4));
    int* blockHist = (int*)(w + take((size_t)nb * 8 * 4));
    int* blockOff  = (int*)(w + take((size_t)nb * 8 * 4));
    int* kcnt      = (int*)(w + take(8 * 4));
    int* ebase     = (int*)(w + take(8 * 4));
    int* ndropped  = (int*)(w + take(4));
    int* gather    = (int*)(w + take((size_t)E * N * 4));
    int* tokmap    = (int*)(w + take((size_t)N * 4));
    int* dropped   = (int*)(w + take((size_t)N * 4));
    size_t small_need = off;
    __hip_bfloat16* Xg   = (__hip_bfloat16*)(w + take((size_t)(N + 128) * D * 2));
    __hip_bfloat16* We16 = (__hip_bfloat16*)(w + take((size_t)E * F * D * 2));
    size_t full_need = off;

    bool fast = (ws_size >= full_need);

    // router + bookkeeping (shared by both paths)
    router_kernel<<<(N + 3) / 4, 256, 0, stream>>>(x, Wr, br, ids, N, D);
    hist_kernel<<<nb, 256, 0, stream>>>(ids, blockHist, N);
    scan_kernel<<<1, 64, 0, stream>>>(blockHist, blockOff, kcnt, ebase, capacity, nb);

    if (fast) {
        hipMemsetAsync(ndropped, 0, 4, stream);
        rank_kernel<<<nb, 256, 0, stream>>>(ids, blockOff, capacity,
                                            gather, dropped, ndropped, N);
        conv_we_kernel<<<2048, 256, 0, stream>>>(We, We16, (size_t)E * F * D);
        {
            dim3 g(512, E);   // 512*16 = 8192 rows max per expert
            gather_conv_x_kernel<<<g, 256, 0, stream>>>(x, gather, kcnt, ebase,
                                                        tokmap, Xg, N, D);
        }
        {
            dim3 g(F / TN, 64, E);   // 64*128 = 8192 rows max; early-exit
            expert_gemm_mfma<<<g, 256, 0, stream>>>(Xg, We16, be, kcnt, ebase,
                                                    tokmap, out, D, F);
        }
        copy_dropped_kernel<<<256, 256, 0, stream>>>(x, dropped, ndropped, out, D);
    } else {
        // fallback: full passthrough + fp32 GEMM (round-1 behavior)
        if (small_need <= ws_size) {
            hipMemcpyAsync(out, x, (size_t)N * D * sizeof(float),
                           hipMemcpyDeviceToDevice, stream);
            rank_kernel<<<nb, 256, 0, stream>>>(ids, blockOff, capacity,
                                                gather, nullptr, nullptr, N);
            dim3 g(F / BN, 128, E);
            expert_gemm_f32<<<g, 256, 0, stream>>>(x, We, be, gather, kcnt,
                                                   out, N, D, F);
        }
    }
}